// Round 1
// baseline (2033.403 us; speedup 1.0000x reference)
//
#include <hip/hip_runtime.h>
#include <stdint.h>

// Grid-encode: L=16 levels, C=2, D=3, H=16, per_level_scale=2, hashmap 2^19.
// Level constants (hardcoded from reference _level_cfg):
//   scale_l = (16<<l) - 1, R_l = (16<<l)+1
//   offsets: l0=0, l1=4920, l2=40864, l>=3: 315496 + (l-3)*524288
//   levels 0-2 tiled (no mod needed: R^3 <= size), levels 3-15 hashed (& 0x7FFFF)

static constexpr uint32_t HASH_MASK = (1u << 19) - 1u;

__global__ __launch_bounds__(256) void grid_enc_kernel(
    const float* __restrict__ xin,
    const float2* __restrict__ ex,
    const float2* __restrict__ ey,
    const float2* __restrict__ ez,
    float* __restrict__ out)
{
    const int tid = blockIdx.x * blockDim.x + threadIdx.x;
    const int b = tid >> 4;   // point index
    const int l = tid & 15;   // level index

    // x = (inputs + 1) / 2  (bound = 1); exact halving, matches fp32 reference
    const float v0 = xin[b * 3 + 0];
    const float v1 = xin[b * 3 + 1];
    const float v2 = xin[b * 3 + 2];
    const float x0 = __fmul_rn(__fadd_rn(v0, 1.0f), 0.5f);
    const float x1 = __fmul_rn(__fadd_rn(v1, 1.0f), 0.5f);
    const float x2 = __fmul_rn(__fadd_rn(v2, 1.0f), 0.5f);

    // pos = x*scale + 0.5 — NON-CONTRACTED fp32 (must match reference rounding;
    // an fma here can flip floor() near cell boundaries -> wrong corners)
    const float scale = (float)((16u << l) - 1u);
    const float p0 = __fadd_rn(__fmul_rn(x0, scale), 0.5f);
    const float p1 = __fadd_rn(__fmul_rn(x1, scale), 0.5f);
    const float p2 = __fadd_rn(__fmul_rn(x2, scale), 0.5f);

    const float fl0 = floorf(p0), fl1 = floorf(p1), fl2 = floorf(p2);
    const float fr0 = __fsub_rn(p0, fl0);
    const float fr1 = __fsub_rn(p1, fl1);
    const float fr2 = __fsub_rn(p2, fl2);
    const float g0 = __fsub_rn(1.0f, fr0);
    const float g1 = __fsub_rn(1.0f, fr1);
    const float g2 = __fsub_rn(1.0f, fr2);
    const uint32_t pg0 = (uint32_t)fl0;
    const uint32_t pg1 = (uint32_t)fl1;
    const uint32_t pg2 = (uint32_t)fl2;

    const uint32_t R = (16u << l) + 1u;              // only meaningful for l<3
    const bool use_hash = (l >= 3);
    const uint32_t offset =
        use_hash ? (315496u + (uint32_t)(l - 3) * 524288u)
                 : (l == 0 ? 0u : (l == 1 ? 4920u : 40864u));

    float a0 = 0.f, a1 = 0.f, a2 = 0.f, a3 = 0.f, a4 = 0.f, a5 = 0.f;

#pragma unroll
    for (int corner = 0; corner < 8; ++corner) {
        const uint32_t b0 = corner & 1;
        const uint32_t b1 = (corner >> 1) & 1;
        const uint32_t b2 = (corner >> 2) & 1;
        const uint32_t c0 = pg0 + b0;
        const uint32_t c1 = pg1 + b1;
        const uint32_t c2 = pg2 + b2;

        // weight: ((w_d0 * w_d1) * w_d2) — same order as jnp.prod
        const float w01 = __fmul_rn(b0 ? fr0 : g0, b1 ? fr1 : g1);
        const float w = __fmul_rn(w01, b2 ? fr2 : g2);

        // both index forms computed, predicated select (no wave divergence)
        const uint32_t idx_t = c0 + c1 * R + c2 * R * R;
        const uint32_t idx_h =
            (c0 * 1u ^ c1 * 2654435761u ^ c2 * 805459861u) & HASH_MASK;
        const uint32_t idx = (use_hash ? idx_h : idx_t) + offset;

        const float2 wx = ex[idx];
        const float2 wy = ey[idx];
        const float2 wz = ez[idx];

        a0 = fmaf(w, wx.x, a0);
        a1 = fmaf(w, wy.x, a1);
        a2 = fmaf(w, wz.x, a2);
        a3 = fmaf(w, wx.y, a3);
        a4 = fmaf(w, wy.y, a4);
        a5 = fmaf(w, wz.y, a5);
    }

    // out[b, (l*2+c)*3 + t]: 6 consecutive floats per thread -> coalesced
    float2* o = (float2*)(out + (size_t)tid * 6);
    o[0] = make_float2(a0, a1);
    o[1] = make_float2(a2, a3);
    o[2] = make_float2(a4, a5);
}

extern "C" void kernel_launch(void* const* d_in, const int* in_sizes, int n_in,
                              void* d_out, int out_size, void* d_ws, size_t ws_size,
                              hipStream_t stream) {
    const float*  xin = (const float*)d_in[0];
    const float2* ex  = (const float2*)d_in[1];
    const float2* ey  = (const float2*)d_in[2];
    const float2* ez  = (const float2*)d_in[3];
    float* out = (float*)d_out;

    const int B = in_sizes[0] / 3;        // 524288
    const int nthreads = B * 16;          // one thread per (point, level)
    dim3 grid(nthreads / 256), block(256);
    grid_enc_kernel<<<grid, block, 0, stream>>>(xin, ex, ey, ez, out);
}

// Round 2
// 1691.406 us; speedup vs baseline: 1.2022x; 1.2022x over previous
//
#include <hip/hip_runtime.h>
#include <stdint.h>

// Grid-encode: L=16 levels, C=2, D=3, H=16, per_level_scale=2, hashmap 2^19.
// Level constants (hardcoded from reference _level_cfg):
//   scale_l = (16<<l) - 1, R_l = (16<<l)+1
//   offsets: l0=0, l1=4920, l2=40864, l>=3: 315496 + (l-3)*524288
//   levels 0-2 tiled, levels 3-15 hashed (& 0x7FFFF)
//
// R2 strategy: interleave the 3 tables into d_ws at 32 B/entry so each corner
// gather touches exactly one 64 B line instead of three.

static constexpr uint32_t HASH_MASK = (1u << 19) - 1u;
static constexpr uint32_t TOTAL_ENTRIES = 315496u + 13u * 524288u;  // 7131240
static constexpr size_t   WS_NEEDED = (size_t)TOTAL_ENTRIES * 32;   // 228 MB

// ---------------------------------------------------------------- build pass
__global__ __launch_bounds__(256) void build_interleaved(
    const float2* __restrict__ ex,
    const float2* __restrict__ ey,
    const float2* __restrict__ ez,
    float4* __restrict__ tbl)   // 2 float4 per entry (32 B)
{
    const uint32_t i = blockIdx.x * blockDim.x + threadIdx.x;
    if (i >= TOTAL_ENTRIES) return;
    const float2 a = ex[i];
    const float2 b = ey[i];
    const float2 c = ez[i];
    tbl[(size_t)i * 2 + 0] = make_float4(a.x, a.y, b.x, b.y);
    tbl[(size_t)i * 2 + 1] = make_float4(c.x, c.y, 0.f, 0.f);
}

// ------------------------------------------------------------- gather pass
__global__ __launch_bounds__(256) void grid_enc_inter(
    const float* __restrict__ xin,
    const float4* __restrict__ tbl,
    float* __restrict__ out)
{
    const int tid = blockIdx.x * blockDim.x + threadIdx.x;
    const int b = tid >> 4;   // point index
    const int l = tid & 15;   // level index

    const float v0 = xin[b * 3 + 0];
    const float v1 = xin[b * 3 + 1];
    const float v2 = xin[b * 3 + 2];
    const float x0 = __fmul_rn(__fadd_rn(v0, 1.0f), 0.5f);
    const float x1 = __fmul_rn(__fadd_rn(v1, 1.0f), 0.5f);
    const float x2 = __fmul_rn(__fadd_rn(v2, 1.0f), 0.5f);

    // pos = x*scale + 0.5 — NON-CONTRACTED fp32 (fma would flip floor() near
    // cell boundaries -> wrong corner selection vs fp32 reference)
    const float scale = (float)((16u << l) - 1u);
    const float p0 = __fadd_rn(__fmul_rn(x0, scale), 0.5f);
    const float p1 = __fadd_rn(__fmul_rn(x1, scale), 0.5f);
    const float p2 = __fadd_rn(__fmul_rn(x2, scale), 0.5f);

    const float fl0 = floorf(p0), fl1 = floorf(p1), fl2 = floorf(p2);
    const float fr0 = __fsub_rn(p0, fl0);
    const float fr1 = __fsub_rn(p1, fl1);
    const float fr2 = __fsub_rn(p2, fl2);
    const float g0 = __fsub_rn(1.0f, fr0);
    const float g1 = __fsub_rn(1.0f, fr1);
    const float g2 = __fsub_rn(1.0f, fr2);
    const uint32_t pg0 = (uint32_t)fl0;
    const uint32_t pg1 = (uint32_t)fl1;
    const uint32_t pg2 = (uint32_t)fl2;

    const uint32_t R = (16u << l) + 1u;
    const bool use_hash = (l >= 3);
    const uint32_t offset =
        use_hash ? (315496u + (uint32_t)(l - 3) * 524288u)
                 : (l == 0 ? 0u : (l == 1 ? 4920u : 40864u));

    float a0 = 0.f, a1 = 0.f, a2 = 0.f, a3 = 0.f, a4 = 0.f, a5 = 0.f;

#pragma unroll
    for (int corner = 0; corner < 8; ++corner) {
        const uint32_t b0 = corner & 1;
        const uint32_t b1 = (corner >> 1) & 1;
        const uint32_t b2 = (corner >> 2) & 1;
        const uint32_t c0 = pg0 + b0;
        const uint32_t c1 = pg1 + b1;
        const uint32_t c2 = pg2 + b2;

        const float w01 = __fmul_rn(b0 ? fr0 : g0, b1 ? fr1 : g1);
        const float w = __fmul_rn(w01, b2 ? fr2 : g2);

        const uint32_t idx_t = c0 + c1 * R + c2 * R * R;
        const uint32_t idx_h =
            (c0 * 1u ^ c1 * 2654435761u ^ c2 * 805459861u) & HASH_MASK;
        const uint32_t idx = (use_hash ? idx_h : idx_t) + offset;

        // one 32B-aligned entry -> exactly one 64B line per corner
        const float4 u = tbl[(size_t)idx * 2 + 0];         // ex.xy, ey.xy
        const float2 v = *(const float2*)(tbl + (size_t)idx * 2 + 1);  // ez.xy

        a0 = fmaf(w, u.x, a0);
        a3 = fmaf(w, u.y, a3);
        a1 = fmaf(w, u.z, a1);
        a4 = fmaf(w, u.w, a4);
        a2 = fmaf(w, v.x, a2);
        a5 = fmaf(w, v.y, a5);
    }

    float2* o = (float2*)(out + (size_t)tid * 6);
    o[0] = make_float2(a0, a1);
    o[1] = make_float2(a2, a3);
    o[2] = make_float2(a4, a5);
}

// ------------------------------------------------- fallback (round-1 kernel)
__global__ __launch_bounds__(256) void grid_enc_kernel(
    const float* __restrict__ xin,
    const float2* __restrict__ ex,
    const float2* __restrict__ ey,
    const float2* __restrict__ ez,
    float* __restrict__ out)
{
    const int tid = blockIdx.x * blockDim.x + threadIdx.x;
    const int b = tid >> 4;
    const int l = tid & 15;

    const float v0 = xin[b * 3 + 0];
    const float v1 = xin[b * 3 + 1];
    const float v2 = xin[b * 3 + 2];
    const float x0 = __fmul_rn(__fadd_rn(v0, 1.0f), 0.5f);
    const float x1 = __fmul_rn(__fadd_rn(v1, 1.0f), 0.5f);
    const float x2 = __fmul_rn(__fadd_rn(v2, 1.0f), 0.5f);

    const float scale = (float)((16u << l) - 1u);
    const float p0 = __fadd_rn(__fmul_rn(x0, scale), 0.5f);
    const float p1 = __fadd_rn(__fmul_rn(x1, scale), 0.5f);
    const float p2 = __fadd_rn(__fmul_rn(x2, scale), 0.5f);

    const float fl0 = floorf(p0), fl1 = floorf(p1), fl2 = floorf(p2);
    const float fr0 = __fsub_rn(p0, fl0);
    const float fr1 = __fsub_rn(p1, fl1);
    const float fr2 = __fsub_rn(p2, fl2);
    const float g0 = __fsub_rn(1.0f, fr0);
    const float g1 = __fsub_rn(1.0f, fr1);
    const float g2 = __fsub_rn(1.0f, fr2);
    const uint32_t pg0 = (uint32_t)fl0;
    const uint32_t pg1 = (uint32_t)fl1;
    const uint32_t pg2 = (uint32_t)fl2;

    const uint32_t R = (16u << l) + 1u;
    const bool use_hash = (l >= 3);
    const uint32_t offset =
        use_hash ? (315496u + (uint32_t)(l - 3) * 524288u)
                 : (l == 0 ? 0u : (l == 1 ? 4920u : 40864u));

    float a0 = 0.f, a1 = 0.f, a2 = 0.f, a3 = 0.f, a4 = 0.f, a5 = 0.f;

#pragma unroll
    for (int corner = 0; corner < 8; ++corner) {
        const uint32_t b0 = corner & 1;
        const uint32_t b1 = (corner >> 1) & 1;
        const uint32_t b2 = (corner >> 2) & 1;
        const uint32_t c0 = pg0 + b0;
        const uint32_t c1 = pg1 + b1;
        const uint32_t c2 = pg2 + b2;

        const float w01 = __fmul_rn(b0 ? fr0 : g0, b1 ? fr1 : g1);
        const float w = __fmul_rn(w01, b2 ? fr2 : g2);

        const uint32_t idx_t = c0 + c1 * R + c2 * R * R;
        const uint32_t idx_h =
            (c0 * 1u ^ c1 * 2654435761u ^ c2 * 805459861u) & HASH_MASK;
        const uint32_t idx = (use_hash ? idx_h : idx_t) + offset;

        const float2 wx = ex[idx];
        const float2 wy = ey[idx];
        const float2 wz = ez[idx];

        a0 = fmaf(w, wx.x, a0);
        a1 = fmaf(w, wy.x, a1);
        a2 = fmaf(w, wz.x, a2);
        a3 = fmaf(w, wx.y, a3);
        a4 = fmaf(w, wy.y, a4);
        a5 = fmaf(w, wz.y, a5);
    }

    float2* o = (float2*)(out + (size_t)tid * 6);
    o[0] = make_float2(a0, a1);
    o[1] = make_float2(a2, a3);
    o[2] = make_float2(a4, a5);
}

extern "C" void kernel_launch(void* const* d_in, const int* in_sizes, int n_in,
                              void* d_out, int out_size, void* d_ws, size_t ws_size,
                              hipStream_t stream) {
    const float*  xin = (const float*)d_in[0];
    const float2* ex  = (const float2*)d_in[1];
    const float2* ey  = (const float2*)d_in[2];
    const float2* ez  = (const float2*)d_in[3];
    float* out = (float*)d_out;

    const int B = in_sizes[0] / 3;        // 524288
    const int nthreads = B * 16;          // one thread per (point, level)

    if (ws_size >= WS_NEEDED) {
        float4* tbl = (float4*)d_ws;
        const int bgrid = (TOTAL_ENTRIES + 255) / 256;
        build_interleaved<<<bgrid, 256, 0, stream>>>(ex, ey, ez, tbl);
        grid_enc_inter<<<nthreads / 256, 256, 0, stream>>>(xin, tbl, out);
    } else {
        grid_enc_kernel<<<nthreads / 256, 256, 0, stream>>>(xin, ex, ey, ez, out);
    }
}

// Round 3
// 1535.770 us; speedup vs baseline: 1.3240x; 1.1013x over previous
//
#include <hip/hip_runtime.h>
#include <stdint.h>

// Grid-encode: L=16, C=2, D=3, H=16, per_level_scale=2, hashmap 2^19.
//   scale_l = (16<<l)-1, R_l = (16<<l)+1
//   offsets: l0=0, l1=4920, l2=40864, l>=3: 315496 + (l-3)*524288
//   levels 0-2 tiled, levels 3-15 hashed (& 0x7FFFF)
//
// R3 strategy: LEVEL-MAJOR block ordering. All blocks of a level run ~together,
// so the live random working set is one level's interleaved table (<=16 MB),
// which L3 (256 MB) retains -> HBM fetch collapses toward compulsory traffic.
// Results staged level-major in ws (coalesced), then transposed to out.

static constexpr uint32_t HASH_MASK = (1u << 19) - 1u;
static constexpr uint32_t TOTAL_ENTRIES = 315496u + 13u * 524288u;  // 7131240
static constexpr size_t   TBL_BYTES = (size_t)TOTAL_ENTRIES * 32;   // ~228 MB

// ---------------------------------------------------------------- build pass
__global__ __launch_bounds__(256) void build_interleaved(
    const float2* __restrict__ ex,
    const float2* __restrict__ ey,
    const float2* __restrict__ ez,
    float4* __restrict__ tbl)   // 2 float4 per entry (32 B)
{
    const uint32_t i = blockIdx.x * blockDim.x + threadIdx.x;
    if (i >= TOTAL_ENTRIES) return;
    const float2 a = ex[i];
    const float2 b = ey[i];
    const float2 c = ez[i];
    tbl[(size_t)i * 2 + 0] = make_float4(a.x, a.y, b.x, b.y);
    tbl[(size_t)i * 2 + 1] = make_float4(c.x, c.y, 0.f, 0.f);
}

// ----------------------------------------------------- shared gather helper
__device__ __forceinline__ void gather_one(
    const float* __restrict__ xin, const float4* __restrict__ tbl,
    int b, int level, float2* __restrict__ dst /* 3 x float2, coalesced */)
{
    const float v0 = xin[b * 3 + 0];
    const float v1 = xin[b * 3 + 1];
    const float v2 = xin[b * 3 + 2];
    const float x0 = __fmul_rn(__fadd_rn(v0, 1.0f), 0.5f);
    const float x1 = __fmul_rn(__fadd_rn(v1, 1.0f), 0.5f);
    const float x2 = __fmul_rn(__fadd_rn(v2, 1.0f), 0.5f);

    // pos = x*scale + 0.5 — NON-CONTRACTED fp32 (fma would flip floor() near
    // cell boundaries -> wrong corner selection vs fp32 reference)
    const float scale = (float)((16u << level) - 1u);
    const float p0 = __fadd_rn(__fmul_rn(x0, scale), 0.5f);
    const float p1 = __fadd_rn(__fmul_rn(x1, scale), 0.5f);
    const float p2 = __fadd_rn(__fmul_rn(x2, scale), 0.5f);

    const float fl0 = floorf(p0), fl1 = floorf(p1), fl2 = floorf(p2);
    const float fr0 = __fsub_rn(p0, fl0);
    const float fr1 = __fsub_rn(p1, fl1);
    const float fr2 = __fsub_rn(p2, fl2);
    const float g0 = __fsub_rn(1.0f, fr0);
    const float g1 = __fsub_rn(1.0f, fr1);
    const float g2 = __fsub_rn(1.0f, fr2);
    const uint32_t pg0 = (uint32_t)fl0;
    const uint32_t pg1 = (uint32_t)fl1;
    const uint32_t pg2 = (uint32_t)fl2;

    // level is block-uniform -> all of these are scalar (SGPR)
    const uint32_t R = (16u << level) + 1u;
    const bool use_hash = (level >= 3);
    const uint32_t offset =
        use_hash ? (315496u + (uint32_t)(level - 3) * 524288u)
                 : (level == 0 ? 0u : (level == 1 ? 4920u : 40864u));

    float a0 = 0.f, a1 = 0.f, a2 = 0.f, a3 = 0.f, a4 = 0.f, a5 = 0.f;

#pragma unroll
    for (int corner = 0; corner < 8; ++corner) {
        const uint32_t b0 = corner & 1;
        const uint32_t b1 = (corner >> 1) & 1;
        const uint32_t b2 = (corner >> 2) & 1;
        const uint32_t c0 = pg0 + b0;
        const uint32_t c1 = pg1 + b1;
        const uint32_t c2 = pg2 + b2;

        const float w01 = __fmul_rn(b0 ? fr0 : g0, b1 ? fr1 : g1);
        const float w = __fmul_rn(w01, b2 ? fr2 : g2);

        const uint32_t idx_t = c0 + c1 * R + c2 * R * R;
        const uint32_t idx_h =
            (c0 * 1u ^ c1 * 2654435761u ^ c2 * 805459861u) & HASH_MASK;
        const uint32_t idx = (use_hash ? idx_h : idx_t) + offset;

        const float4 u = tbl[(size_t)idx * 2 + 0];                     // ex, ey
        const float2 v = *(const float2*)(tbl + (size_t)idx * 2 + 1);  // ez

        a0 = fmaf(w, u.x, a0);
        a3 = fmaf(w, u.y, a3);
        a1 = fmaf(w, u.z, a1);
        a4 = fmaf(w, u.w, a4);
        a2 = fmaf(w, v.x, a2);
        a5 = fmaf(w, v.y, a5);
    }

    dst[0] = make_float2(a0, a1);
    dst[1] = make_float2(a2, a3);
    dst[2] = make_float2(a4, a5);
}

// ------------------------------------------ phase A: level-major gather -> ws
__global__ __launch_bounds__(256) void gather_level_major(
    const float* __restrict__ xin,
    const float4* __restrict__ tbl,
    float* __restrict__ staged,   // [16][B][6] floats
    int B, int nchunks)
{
    const int level = blockIdx.x / nchunks;
    const int chunk = blockIdx.x - level * nchunks;
    const int b = chunk * 256 + threadIdx.x;
    float2* dst = (float2*)(staged + ((size_t)level * B + b) * 6);
    gather_one(xin, tbl, b, level, dst);
}

// --------------------------------- phase A': level-major, direct strided out
__global__ __launch_bounds__(256) void gather_level_major_direct(
    const float* __restrict__ xin,
    const float4* __restrict__ tbl,
    float* __restrict__ out,      // [B][96]
    int B, int nchunks)
{
    const int level = blockIdx.x / nchunks;
    const int chunk = blockIdx.x - level * nchunks;
    const int b = chunk * 256 + threadIdx.x;
    float2* dst = (float2*)(out + (size_t)b * 96 + level * 6);
    gather_one(xin, tbl, b, level, dst);
}

// ------------------------------------------------ phase B: transpose -> out
__global__ __launch_bounds__(256) void transpose_out(
    const float2* __restrict__ staged,  // [16][B][3] float2
    float2* __restrict__ out,           // [B][48] float2
    int B)
{
    const int b = blockIdx.x * 256 + threadIdx.x;
#pragma unroll
    for (int l = 0; l < 16; ++l) {
        const float2* src = staged + ((size_t)l * B + b) * 3;
        float2* dst = out + (size_t)b * 48 + l * 3;
        const float2 s0 = src[0], s1 = src[1], s2 = src[2];
        dst[0] = s0; dst[1] = s1; dst[2] = s2;
    }
}

// ------------------------------------------------- fallback (round-1 kernel)
__global__ __launch_bounds__(256) void grid_enc_kernel(
    const float* __restrict__ xin,
    const float2* __restrict__ ex,
    const float2* __restrict__ ey,
    const float2* __restrict__ ez,
    float* __restrict__ out)
{
    const int tid = blockIdx.x * blockDim.x + threadIdx.x;
    const int b = tid >> 4;
    const int l = tid & 15;

    const float v0 = xin[b * 3 + 0];
    const float v1 = xin[b * 3 + 1];
    const float v2 = xin[b * 3 + 2];
    const float x0 = __fmul_rn(__fadd_rn(v0, 1.0f), 0.5f);
    const float x1 = __fmul_rn(__fadd_rn(v1, 1.0f), 0.5f);
    const float x2 = __fmul_rn(__fadd_rn(v2, 1.0f), 0.5f);

    const float scale = (float)((16u << l) - 1u);
    const float p0 = __fadd_rn(__fmul_rn(x0, scale), 0.5f);
    const float p1 = __fadd_rn(__fmul_rn(x1, scale), 0.5f);
    const float p2 = __fadd_rn(__fmul_rn(x2, scale), 0.5f);

    const float fl0 = floorf(p0), fl1 = floorf(p1), fl2 = floorf(p2);
    const float fr0 = __fsub_rn(p0, fl0);
    const float fr1 = __fsub_rn(p1, fl1);
    const float fr2 = __fsub_rn(p2, fl2);
    const float g0 = __fsub_rn(1.0f, fr0);
    const float g1 = __fsub_rn(1.0f, fr1);
    const float g2 = __fsub_rn(1.0f, fr2);
    const uint32_t pg0 = (uint32_t)fl0;
    const uint32_t pg1 = (uint32_t)fl1;
    const uint32_t pg2 = (uint32_t)fl2;

    const uint32_t R = (16u << l) + 1u;
    const bool use_hash = (l >= 3);
    const uint32_t offset =
        use_hash ? (315496u + (uint32_t)(l - 3) * 524288u)
                 : (l == 0 ? 0u : (l == 1 ? 4920u : 40864u));

    float a0 = 0.f, a1 = 0.f, a2 = 0.f, a3 = 0.f, a4 = 0.f, a5 = 0.f;

#pragma unroll
    for (int corner = 0; corner < 8; ++corner) {
        const uint32_t b0 = corner & 1;
        const uint32_t b1 = (corner >> 1) & 1;
        const uint32_t b2 = (corner >> 2) & 1;
        const uint32_t c0 = pg0 + b0;
        const uint32_t c1 = pg1 + b1;
        const uint32_t c2 = pg2 + b2;

        const float w01 = __fmul_rn(b0 ? fr0 : g0, b1 ? fr1 : g1);
        const float w = __fmul_rn(w01, b2 ? fr2 : g2);

        const uint32_t idx_t = c0 + c1 * R + c2 * R * R;
        const uint32_t idx_h =
            (c0 * 1u ^ c1 * 2654435761u ^ c2 * 805459861u) & HASH_MASK;
        const uint32_t idx = (use_hash ? idx_h : idx_t) + offset;

        const float2 wx = ex[idx];
        const float2 wy = ey[idx];
        const float2 wz = ez[idx];

        a0 = fmaf(w, wx.x, a0);
        a1 = fmaf(w, wy.x, a1);
        a2 = fmaf(w, wz.x, a2);
        a3 = fmaf(w, wx.y, a3);
        a4 = fmaf(w, wy.y, a4);
        a5 = fmaf(w, wz.y, a5);
    }

    float2* o = (float2*)(out + (size_t)tid * 6);
    o[0] = make_float2(a0, a1);
    o[1] = make_float2(a2, a3);
    o[2] = make_float2(a4, a5);
}

extern "C" void kernel_launch(void* const* d_in, const int* in_sizes, int n_in,
                              void* d_out, int out_size, void* d_ws, size_t ws_size,
                              hipStream_t stream) {
    const float*  xin = (const float*)d_in[0];
    const float2* ex  = (const float2*)d_in[1];
    const float2* ey  = (const float2*)d_in[2];
    const float2* ez  = (const float2*)d_in[3];
    float* out = (float*)d_out;

    const int B = in_sizes[0] / 3;             // 524288
    const int nchunks = (B + 255) / 256;       // blocks per level
    const size_t staged_bytes = (size_t)B * 96 * 4;  // ~201 MB

    if (ws_size >= TBL_BYTES + staged_bytes) {
        float4* tbl = (float4*)d_ws;
        float* staged = (float*)((char*)d_ws + TBL_BYTES);
        build_interleaved<<<(TOTAL_ENTRIES + 255) / 256, 256, 0, stream>>>(ex, ey, ez, tbl);
        gather_level_major<<<16 * nchunks, 256, 0, stream>>>(xin, tbl, staged, B, nchunks);
        transpose_out<<<nchunks, 256, 0, stream>>>((const float2*)staged, (float2*)out, B);
    } else if (ws_size >= TBL_BYTES) {
        float4* tbl = (float4*)d_ws;
        build_interleaved<<<(TOTAL_ENTRIES + 255) / 256, 256, 0, stream>>>(ex, ey, ez, tbl);
        gather_level_major_direct<<<16 * nchunks, 256, 0, stream>>>(xin, tbl, out, B, nchunks);
    } else {
        grid_enc_kernel<<<(B * 16) / 256, 256, 0, stream>>>(xin, ex, ey, ez, out);
    }
}